// Round 14
// baseline (59.280 us; speedup 1.0000x reference)
//
#include <hip/hip_runtime.h>
#include <math.h>

#define BS   4
#define V    4096
#define NB   50
#define IC   64
#define OC   64
#define SUP  4
#define WCOL 320
#define WT_STRIDE 72     // shorts; 144B row -> 2-way LDS bank aliasing (free)
#define CH   10          // neighbors per pipeline chunk (5 chunks of 10)

typedef float    f32x4 __attribute__((ext_vector_type(4)));
typedef short    s16x8 __attribute__((ext_vector_type(8)));
typedef _Float16 h16x2 __attribute__((ext_vector_type(2)));

typedef const __attribute__((address_space(1))) unsigned GU;
typedef __attribute__((address_space(3))) unsigned LU;

__device__ inline unsigned short bf16r(float f) {          // RNE f32->bf16
    unsigned u = __builtin_bit_cast(unsigned, f);
    u += 0x7FFFu + ((u >> 16) & 1u);
    return (unsigned short)(u >> 16);
}
__device__ inline unsigned short f16b(float f) {           // f32->f16 bits
    return __builtin_bit_cast(unsigned short, (_Float16)f);
}
__device__ inline float fdot2acc(h16x2 a, h16x2 b, float c) {
#if __has_builtin(__builtin_amdgcn_fdot2)
    return __builtin_amdgcn_fdot2(a, b, c, false);   // v_dot2_f32_f16
#else
    return c + (float)a.x * (float)b.x + (float)a.y * (float)b.y;
#endif
}
__device__ inline void gll4(const void* g, void* l) {      // 4B/lane -> LDS
    __builtin_amdgcn_global_load_lds((GU*)g, (LU*)l, 4, 0, 0);
}

// ---------------------------------------------------------------------------
// Kernel 1 (MFMA): feature_out = fm @ W + bias.
//   out[row*64 + c]          = feature_out[row][c]          (center -> d_out)
//   fo_s[(row*64 + c)*4 + s] = f16(feature_out[row][64+s*64+c])
// ---------------------------------------------------------------------------
__global__ __launch_bounds__(256) void feat_kernel(
    const float* __restrict__ fm,    // (16384, 64)
    const float* __restrict__ W,     // (64, 320)
    const float* __restrict__ bias,  // (320,)
    float* __restrict__ out,         // (16384, 64)  center slice
    unsigned short* __restrict__ fo_s)  // f16
{
    __shared__ unsigned short wt[WCOL * WT_STRIDE];  // wt[col][k], 45 KB
    const int t = threadIdx.x;

#pragma unroll
    for (int i = 0; i < 20; ++i) {
        const int idx4 = t + i * 256;
        const int e    = idx4 * 4;
        const int k    = e / WCOL;
        const int col  = e - k * WCOL;
        const float4 v = reinterpret_cast<const float4*>(W)[idx4];
        wt[(col + 0) * WT_STRIDE + k] = bf16r(v.x);
        wt[(col + 1) * WT_STRIDE + k] = bf16r(v.y);
        wt[(col + 2) * WT_STRIDE + k] = bf16r(v.z);
        wt[(col + 3) * WT_STRIDE + k] = bf16r(v.w);
    }
    __syncthreads();

    const int w   = t >> 6;
    const int l   = t & 63;
    const int rlo = l & 15;
    const int kg  = l >> 4;
    const int row = blockIdx.x * 64 + w * 16 + rlo;

    const float* fr = &fm[row * IC + kg * 8];
    s16x8 a0, a1;
#pragma unroll
    for (int e = 0; e < 8; ++e) {
        a0[e] = (short)bf16r(fr[e]);
        a1[e] = (short)bf16r(fr[32 + e]);
    }

    const int drow0 = blockIdx.x * 64 + w * 16 + kg * 4;
#pragma unroll
    for (int ct = 0; ct < 20; ++ct) {
        const int col = ct * 16 + rlo;
        const s16x8 b0 = *reinterpret_cast<const s16x8*>(&wt[col * WT_STRIDE + kg * 8]);
        const s16x8 b1 = *reinterpret_cast<const s16x8*>(&wt[col * WT_STRIDE + 32 + kg * 8]);
        f32x4 acc = {0.f, 0.f, 0.f, 0.f};
        acc = __builtin_amdgcn_mfma_f32_16x16x32_bf16(a0, b0, acc, 0, 0, 0);
        acc = __builtin_amdgcn_mfma_f32_16x16x32_bf16(a1, b1, acc, 0, 0, 0);
        const float bv = bias[col];
        if (ct < 4) {
#pragma unroll
            for (int r = 0; r < 4; ++r)
                out[(drow0 + r) * OC + col] = acc[r] + bv;
        } else {
            const int cc = (col - OC) & 63;
            const int s  = (col - OC) >> 6;
#pragma unroll
            for (int r = 0; r < 4; ++r)
                fo_s[((drow0 + r) * OC + cc) * SUP + s] =
                    __builtin_bit_cast(unsigned short, (_Float16)(acc[r] + bv));
        }
    }
}

// ---------------------------------------------------------------------------
// Kernel 2 (conv): wave = 1 row. Table in registers-across-lanes (readlane).
// Gathers via global_load_lds into a WAVE-PRIVATE LDS slot (no barriers):
// zero VGPR cost per in-flight load -> ~20 outstanding 256B loads per wave.
// Counted vmcnt(20): next chunk's loads stay in flight across the compute.
// RACE FIX vs r13: drain lgkmcnt(0)+sched_barrier after each compute chunk
// BEFORE issuing the DMA that overwrites that LDS buffer (ds_read vs DMA
// write ordering is otherwise unguaranteed).
// ---------------------------------------------------------------------------
__global__ __launch_bounds__(256) void conv_kernel(
    const int*   __restrict__ nidx,   // (BS, V, 50)
    const float* __restrict__ verts,  // (BS, V, 3)
    const float* __restrict__ nval,   // (BS, V, 50)
    const float* __restrict__ dirs,   // (3, 256)
    const unsigned short* __restrict__ fo_s, // (16384, 64, 4) f16
    float* __restrict__ out)          // (16384, 64) holds center on entry
{
    const int bid = blockIdx.x;                     // 0..4095
    const int swz = ((bid & 7) << 9) + (bid >> 3);  // XCD bijection on 4096
    const int wv  = threadIdx.x >> 6;
    const int l   = threadIdx.x & 63;               // lane = channel
    const int row = swz * 4 + wv;
    const int b   = swz >> 10;

    // wave-private staging: [wave][dbuf][CH*512 B]
    __shared__ uint4 sbuf[4][2][CH * 32];
    char* const b0p = (char*)&sbuf[wv][0][0];
    char* const b1p = (char*)&sbuf[wv][1][0];

    // f16 direction-column pairs: component = support {0,1} / {2,3}
    h16x2 cs01x, cs01y, cs01z, cs23x, cs23y, cs23z;
    {
        float sx[4], sy[4], sz[4];
#pragma unroll
        for (int s = 0; s < 4; ++s) {
            const int col = s * 64 + l;
            const float d0 = dirs[col], d1 = dirs[256 + col], d2 = dirs[512 + col];
            const float inv = 1.f / fmaxf(sqrtf(d0 * d0 + d1 * d1 + d2 * d2), 1e-12f);
            sx[s] = d0 * inv; sy[s] = d1 * inv; sz[s] = d2 * inv;
        }
        cs01x = (h16x2){ (_Float16)sx[0], (_Float16)sx[1] };
        cs01y = (h16x2){ (_Float16)sy[0], (_Float16)sy[1] };
        cs01z = (h16x2){ (_Float16)sz[0], (_Float16)sz[1] };
        cs23x = (h16x2){ (_Float16)sx[2], (_Float16)sx[3] };
        cs23y = (h16x2){ (_Float16)sy[2], (_Float16)sy[3] };
        cs23z = (h16x2){ (_Float16)sz[2], (_Float16)sz[3] };
    }

    // per-row setup: lane j<50 builds packed f16 dirs + byte offset for j
    unsigned ex = 0, ey = 0, ez = 0, eo = 0;
    {
        const float nv = (l < NB) ? nval[(size_t)row * NB + l] : 0.f;
        float ss = nv * nv;
#pragma unroll
        for (int o = 32; o > 0; o >>= 1) ss += __shfl_xor(ss, o);
        const float wn = nv * (1.f / fmaxf(sqrtf(ss), 1e-12f));
        if (l < NB) {
            const int idx = nidx[(size_t)row * NB + l];
            const float* vn = &verts[(size_t)(b * V + idx) * 3];
            const float* vc = &verts[(size_t)row * 3];
            float dx = vn[0] - vc[0], dy = vn[1] - vc[1], dz = vn[2] - vc[2];
            const float inv = 1.f / fmaxf(sqrtf(dx*dx + dy*dy + dz*dz), 1e-12f);
            dx *= inv; dy *= inv; dz *= inv;
            const unsigned hx = f16b(dx), hy = f16b(dy);
            const unsigned hzv = f16b(dz), hw = f16b(wn);
            ex = hx | (hx << 16);
            ey = hy | (hy << 16);
            ez = hzv | (hw << 16);
            eo = ((unsigned)idx) << 9;
        }
    }

    const float ctr = out[(size_t)row * OC + l];

    const char* gbase = (const char*)fo_s + (size_t)b * ((size_t)V * OC * SUP * 2);
    const unsigned l4 = (unsigned)(l << 2);

    float acc0 = 0.f, acc1 = 0.f;
    const h16x2 hz = { (_Float16)0.f, (_Float16)0.f };

#define ISSUE(T, BUFP) _Pragma("unroll") \
    for (int jj = 0; jj < CH; ++jj) { \
        const unsigned off = (unsigned)__builtin_amdgcn_readlane((int)eo, (T) * CH + jj); \
        const char* g = gbase + (size_t)(off + l4); \
        gll4(g,       BUFP + jj * 512); \
        gll4(g + 256, BUFP + jj * 512 + 256); \
    }

#define CCHUNK(T, BUFP) _Pragma("unroll") \
    for (int jj = 0; jj < CH; ++jj) { \
        const int j = (T) * CH + jj; \
        const unsigned ax = (unsigned)__builtin_amdgcn_readlane((int)ex, j); \
        const unsigned ay = (unsigned)__builtin_amdgcn_readlane((int)ey, j); \
        const unsigned az = (unsigned)__builtin_amdgcn_readlane((int)ez, j); \
        const h16x2 dxdx = __builtin_bit_cast(h16x2, ax); \
        const h16x2 dydy = __builtin_bit_cast(h16x2, ay); \
        const unsigned zlo = az & 0xffffu, zhi = az >> 16; \
        const h16x2 dzdz = __builtin_bit_cast(h16x2, zlo | (zlo << 16)); \
        const h16x2 wjwj = __builtin_bit_cast(h16x2, zhi | (zhi << 16)); \
        h16x2 t01 = dxdx * cs01x + dydy * cs01y + dzdz * cs01z; \
        h16x2 t23 = dxdx * cs23x + dydy * cs23y + dzdz * cs23z; \
        t01 = __builtin_elementwise_max(t01, hz); \
        t23 = __builtin_elementwise_max(t23, hz); \
        t01 *= wjwj; t23 *= wjwj; \
        const uint2 gg = *reinterpret_cast<const uint2*>(BUFP + jj * 512 + (l << 3)); \
        acc0 = fdot2acc(t01, __builtin_bit_cast(h16x2, gg.x), acc0); \
        acc1 = fdot2acc(t23, __builtin_bit_cast(h16x2, gg.y), acc1); \
    }

#define WAIT20 { asm volatile("s_waitcnt vmcnt(20)" ::: "memory"); \
                 __builtin_amdgcn_sched_barrier(0); }
#define WAIT0  { asm volatile("s_waitcnt vmcnt(0)"  ::: "memory"); \
                 __builtin_amdgcn_sched_barrier(0); }
#define LDRAIN { asm volatile("s_waitcnt lgkmcnt(0)" ::: "memory"); \
                 __builtin_amdgcn_sched_barrier(0); }

    ISSUE(0, b0p)
    ISSUE(1, b1p) WAIT20 CCHUNK(0, b0p) LDRAIN
    ISSUE(2, b0p) WAIT20 CCHUNK(1, b1p) LDRAIN
    ISSUE(3, b1p) WAIT20 CCHUNK(2, b0p) LDRAIN
    ISSUE(4, b0p) WAIT20 CCHUNK(3, b1p) LDRAIN
                  WAIT0  CCHUNK(4, b0p)

#undef ISSUE
#undef CCHUNK
#undef WAIT20
#undef WAIT0
#undef LDRAIN

    out[(size_t)row * OC + l] = ctr + acc0 + acc1;
}

// ---------------------------------------------------------------------------
extern "C" void kernel_launch(void* const* d_in, const int* in_sizes, int n_in,
                              void* d_out, int out_size, void* d_ws, size_t ws_size,
                              hipStream_t stream) {
    const int*   nidx  = (const int*)  d_in[0];
    const float* verts = (const float*)d_in[1];
    const float* fm    = (const float*)d_in[2];
    const float* nval  = (const float*)d_in[3];
    const float* W     = (const float*)d_in[4];
    const float* bias  = (const float*)d_in[5];
    const float* dirs  = (const float*)d_in[6];
    float*       out   = (float*)d_out;

    unsigned short* fo_s = (unsigned short*)d_ws;     // 8 MiB

    feat_kernel<<<(BS * V) / 64, 256, 0, stream>>>(fm, W, bias, out, fo_s);
    conv_kernel<<<(BS * V) / 4, 256, 0, stream>>>(nidx, verts, nval, dirs,
                                                  fo_s, out);
}

// Round 15
// 48.701 us; speedup vs baseline: 1.2172x; 1.2172x over previous
//
#include <hip/hip_runtime.h>
#include <math.h>

#define BS   4
#define V    4096
#define NB   50
#define IC   64
#define OC   64
#define SUP  4
#define WCOL 320
#define WT_STRIDE 72     // shorts; 144B row -> 2-way LDS bank aliasing (free)

typedef float    f32x4 __attribute__((ext_vector_type(4)));
typedef short    s16x8 __attribute__((ext_vector_type(8)));
typedef _Float16 h16x2 __attribute__((ext_vector_type(2)));

__device__ inline unsigned short bf16r(float f) {          // RNE f32->bf16
    unsigned u = __builtin_bit_cast(unsigned, f);
    u += 0x7FFFu + ((u >> 16) & 1u);
    return (unsigned short)(u >> 16);
}
__device__ inline unsigned short f16b(float f) {           // f32->f16 bits
    return __builtin_bit_cast(unsigned short, (_Float16)f);
}
__device__ inline h16x2 bch(unsigned u) {
    return __builtin_bit_cast(h16x2, u);
}
__device__ inline float fdot2acc(h16x2 a, h16x2 b, float c) {
#if __has_builtin(__builtin_amdgcn_fdot2)
    return __builtin_amdgcn_fdot2(a, b, c, false);   // v_dot2_f32_f16
#else
    return c + (float)a.x * (float)b.x + (float)a.y * (float)b.y;
#endif
}

// ---------------------------------------------------------------------------
// Kernel 1 (MFMA): feature_out = fm @ W + bias.
//   out[row*64 + c]          = feature_out[row][c]          (center -> d_out)
//   fo_s[(row*64 + c)*4 + s] = f16(feature_out[row][64+s*64+c])
// ---------------------------------------------------------------------------
__global__ __launch_bounds__(256) void feat_kernel(
    const float* __restrict__ fm,    // (16384, 64)
    const float* __restrict__ W,     // (64, 320)
    const float* __restrict__ bias,  // (320,)
    float* __restrict__ out,         // (16384, 64)  center slice
    unsigned short* __restrict__ fo_s)  // f16
{
    __shared__ unsigned short wt[WCOL * WT_STRIDE];  // wt[col][k], 45 KB
    const int t = threadIdx.x;

#pragma unroll
    for (int i = 0; i < 20; ++i) {
        const int idx4 = t + i * 256;
        const int e    = idx4 * 4;
        const int k    = e / WCOL;
        const int col  = e - k * WCOL;
        const float4 v = reinterpret_cast<const float4*>(W)[idx4];
        wt[(col + 0) * WT_STRIDE + k] = bf16r(v.x);
        wt[(col + 1) * WT_STRIDE + k] = bf16r(v.y);
        wt[(col + 2) * WT_STRIDE + k] = bf16r(v.z);
        wt[(col + 3) * WT_STRIDE + k] = bf16r(v.w);
    }
    __syncthreads();

    const int w   = t >> 6;
    const int l   = t & 63;
    const int rlo = l & 15;
    const int kg  = l >> 4;
    const int row = blockIdx.x * 64 + w * 16 + rlo;

    const float* fr = &fm[row * IC + kg * 8];
    s16x8 a0, a1;
#pragma unroll
    for (int e = 0; e < 8; ++e) {
        a0[e] = (short)bf16r(fr[e]);
        a1[e] = (short)bf16r(fr[32 + e]);
    }

    const int drow0 = blockIdx.x * 64 + w * 16 + kg * 4;
#pragma unroll
    for (int ct = 0; ct < 20; ++ct) {
        const int col = ct * 16 + rlo;
        const s16x8 b0 = *reinterpret_cast<const s16x8*>(&wt[col * WT_STRIDE + kg * 8]);
        const s16x8 b1 = *reinterpret_cast<const s16x8*>(&wt[col * WT_STRIDE + 32 + kg * 8]);
        f32x4 acc = {0.f, 0.f, 0.f, 0.f};
        acc = __builtin_amdgcn_mfma_f32_16x16x32_bf16(a0, b0, acc, 0, 0, 0);
        acc = __builtin_amdgcn_mfma_f32_16x16x32_bf16(a1, b1, acc, 0, 0, 0);
        const float bv = bias[col];
        if (ct < 4) {
#pragma unroll
            for (int r = 0; r < 4; ++r)
                out[(drow0 + r) * OC + col] = acc[r] + bv;
        } else {
            const int cc = (col - OC) & 63;
            const int s  = (col - OC) >> 6;
#pragma unroll
            for (int r = 0; r < 4; ++r)
                fo_s[((drow0 + r) * OC + cc) * SUP + s] =
                    __builtin_bit_cast(unsigned short, (_Float16)(acc[r] + bv));
        }
    }
}

// ---------------------------------------------------------------------------
// Kernel 2 (conv): wave = 2 rows; lanes 0-31 = row0, lanes 32-63 = row1.
// Each lane owns channel pair (c0=2m, c0+1); ONE dwordx4 gather per j serves
// BOTH rows (halves the VMEM instruction count -> TA pressure).
// Per-(row,j) table in wave-private LDS (ds_read_b128 broadcast per half).
// ---------------------------------------------------------------------------
__global__ __launch_bounds__(256) void conv_kernel(
    const int*   __restrict__ nidx,   // (BS, V, 50)
    const float* __restrict__ verts,  // (BS, V, 3)
    const float* __restrict__ nval,   // (BS, V, 50)
    const float* __restrict__ dirs,   // (3, 256)
    const unsigned short* __restrict__ fo_s, // (16384, 64, 4) f16
    float* __restrict__ out)          // (16384, 64) holds center on entry
{
    const int bid  = blockIdx.x;                     // 0..2047
    const int swz  = ((bid & 7) << 8) + (bid >> 3);  // XCD bijection on 2048
    const int wv   = threadIdx.x >> 6;
    const int l    = threadIdx.x & 63;
    const int half = l >> 5;                         // which row
    const int m    = l & 31;                         // channel-pair index
    const int c0   = m * 2;
    const int row0 = swz * 8 + wv * 2;
    const int row  = row0 + half;
    const int b    = row0 >> 12;                     // block never crosses batch

    __shared__ uint4    tb [4][2][NB];   // {dxdx,dydy,dzdz,wjwj} f16-pairs
    __shared__ unsigned tbo[4][2][NB];   // idx<<9 byte offsets     (8 KB tot)

    // --- per-lane: normalized dir columns for channels c0, c0+1 -----------
    h16x2 ax01, ay01, az01, ax23, ay23, az23;   // channel c0
    h16x2 bx01, by01, bz01, bx23, by23, bz23;   // channel c0+1
    {
        float sx0[4], sy0[4], sz0[4], sx1[4], sy1[4], sz1[4];
#pragma unroll
        for (int s = 0; s < 4; ++s) {
            const int col = s * 64 + c0;
            const float2 d0 = *reinterpret_cast<const float2*>(&dirs[col]);
            const float2 d1 = *reinterpret_cast<const float2*>(&dirs[256 + col]);
            const float2 d2 = *reinterpret_cast<const float2*>(&dirs[512 + col]);
            const float i0 = 1.f / fmaxf(sqrtf(d0.x*d0.x + d1.x*d1.x + d2.x*d2.x), 1e-12f);
            const float i1 = 1.f / fmaxf(sqrtf(d0.y*d0.y + d1.y*d1.y + d2.y*d2.y), 1e-12f);
            sx0[s] = d0.x * i0; sy0[s] = d1.x * i0; sz0[s] = d2.x * i0;
            sx1[s] = d0.y * i1; sy1[s] = d1.y * i1; sz1[s] = d2.y * i1;
        }
        ax01 = (h16x2){(_Float16)sx0[0], (_Float16)sx0[1]};
        ax23 = (h16x2){(_Float16)sx0[2], (_Float16)sx0[3]};
        ay01 = (h16x2){(_Float16)sy0[0], (_Float16)sy0[1]};
        ay23 = (h16x2){(_Float16)sy0[2], (_Float16)sy0[3]};
        az01 = (h16x2){(_Float16)sz0[0], (_Float16)sz0[1]};
        az23 = (h16x2){(_Float16)sz0[2], (_Float16)sz0[3]};
        bx01 = (h16x2){(_Float16)sx1[0], (_Float16)sx1[1]};
        bx23 = (h16x2){(_Float16)sx1[2], (_Float16)sx1[3]};
        by01 = (h16x2){(_Float16)sy1[0], (_Float16)sy1[1]};
        by23 = (h16x2){(_Float16)sy1[2], (_Float16)sy1[3]};
        bz01 = (h16x2){(_Float16)sz1[0], (_Float16)sz1[1]};
        bz23 = (h16x2){(_Float16)sz1[2], (_Float16)sz1[3]};
    }

    // --- build per-(row,j) table in wave-private LDS (lane j<50 = entry j)
#pragma unroll
    for (int ri = 0; ri < 2; ++ri) {
        const int r = row0 + ri;
        const float nv = (l < NB) ? nval[(size_t)r * NB + l] : 0.f;
        float ss = nv * nv;
#pragma unroll
        for (int o = 32; o > 0; o >>= 1) ss += __shfl_xor(ss, o);
        const float wn = nv * (1.f / fmaxf(sqrtf(ss), 1e-12f));
        if (l < NB) {
            const int idx = nidx[(size_t)r * NB + l];
            const float* vn = &verts[(size_t)(b * V + idx) * 3];
            const float* vc = &verts[(size_t)r * 3];
            float dx = vn[0] - vc[0], dy = vn[1] - vc[1], dz = vn[2] - vc[2];
            const float inv = 1.f / fmaxf(sqrtf(dx*dx + dy*dy + dz*dz), 1e-12f);
            dx *= inv; dy *= inv; dz *= inv;
            const unsigned hx = f16b(dx), hy = f16b(dy);
            const unsigned hzv = f16b(dz), hw = f16b(wn);
            uint4 e;
            e.x = hx  | (hx  << 16);
            e.y = hy  | (hy  << 16);
            e.z = hzv | (hzv << 16);
            e.w = hw  | (hw  << 16);
            tb [wv][ri][l] = e;
            tbo[wv][ri][l] = ((unsigned)idx) << 9;
        }
    }
    // wave-private LDS: compiler orders ds_write -> ds_read via lgkmcnt.

    const float2 ctr = *reinterpret_cast<const float2*>(&out[(size_t)row * OC + c0]);

    const char* gb = (const char*)fo_s + (size_t)b * ((size_t)V * OC * SUP * 2)
                   + (unsigned)(m << 4);

    float acc0 = 0.f, acc1 = 0.f;
    const h16x2 hz = { (_Float16)0.f, (_Float16)0.f };

#pragma unroll
    for (int j = 0; j < NB; ++j) {
        const uint4    e   = tb [wv][half][j];
        const unsigned off = tbo[wv][half][j];
        const h16x2 dxdx = bch(e.x), dydy = bch(e.y);
        const h16x2 dzdz = bch(e.z), wjwj = bch(e.w);

        const uint4 g = *reinterpret_cast<const uint4*>(gb + off);

        h16x2 t01a = dxdx * ax01 + dydy * ay01 + dzdz * az01;
        h16x2 t23a = dxdx * ax23 + dydy * ay23 + dzdz * az23;
        h16x2 t01b = dxdx * bx01 + dydy * by01 + dzdz * bz01;
        h16x2 t23b = dxdx * bx23 + dydy * by23 + dzdz * bz23;
        t01a = __builtin_elementwise_max(t01a, hz) * wjwj;
        t23a = __builtin_elementwise_max(t23a, hz) * wjwj;
        t01b = __builtin_elementwise_max(t01b, hz) * wjwj;
        t23b = __builtin_elementwise_max(t23b, hz) * wjwj;

        acc0 = fdot2acc(t01a, bch(g.x), acc0);
        acc0 = fdot2acc(t23a, bch(g.y), acc0);
        acc1 = fdot2acc(t01b, bch(g.z), acc1);
        acc1 = fdot2acc(t23b, bch(g.w), acc1);
    }

    float2 res;
    res.x = ctr.x + acc0;
    res.y = ctr.y + acc1;
    *reinterpret_cast<float2*>(&out[(size_t)row * OC + c0]) = res;
}

// ---------------------------------------------------------------------------
extern "C" void kernel_launch(void* const* d_in, const int* in_sizes, int n_in,
                              void* d_out, int out_size, void* d_ws, size_t ws_size,
                              hipStream_t stream) {
    const int*   nidx  = (const int*)  d_in[0];
    const float* verts = (const float*)d_in[1];
    const float* fm    = (const float*)d_in[2];
    const float* nval  = (const float*)d_in[3];
    const float* W     = (const float*)d_in[4];
    const float* bias  = (const float*)d_in[5];
    const float* dirs  = (const float*)d_in[6];
    float*       out   = (float*)d_out;

    unsigned short* fo_s = (unsigned short*)d_ws;     // 8 MiB

    feat_kernel<<<(BS * V) / 64, 256, 0, stream>>>(fm, W, bias, out, fo_s);
    conv_kernel<<<(BS * V) / 8, 256, 0, stream>>>(nidx, verts, nval, dirs,
                                                  fo_s, out);
}